// Round 5
// baseline (425.350 us; speedup 1.0000x reference)
//
#include <hip/hip_runtime.h>

#define HIDDEN 16
#define N_FEAT 128
#define EMBED 128
#define N_GRAPHS 64
#define BSH 8              // 256 nodes per bucket
#define MAXB 512           // LDS bound on bucket count (nbuck = 391 here)

typedef unsigned int uint;

// bf16x2 pack/unpack (round-to-nearest-even)
__device__ inline uint pk2(float a, float b) {
    uint ua = __float_as_uint(a), ub = __float_as_uint(b);
    ua = (ua + 0x7FFFu + ((ua >> 16) & 1u)) >> 16;
    ub = (ub + 0x7FFFu + ((ub >> 16) & 1u)) & 0xFFFF0000u;
    return ua | ub;
}
__device__ inline float2 upk2(uint w) {
    return make_float2(__uint_as_float(w << 16), __uint_as_float(w & 0xFFFF0000u));
}

// ---- K1: global bucket histogram of dst>>BSH
__global__ void __launch_bounds__(1024)
k_hist(const int* __restrict__ dst, int n_edges, int nbuck, int* __restrict__ ghist) {
    __shared__ int h[MAXB];
    for (int i = threadIdx.x; i < MAXB; i += 1024) h[i] = 0;
    __syncthreads();
    int base = blockIdx.x * 4096;
#pragma unroll
    for (int j = 0; j < 4; j++) {
        int e = base + j * 1024 + threadIdx.x;
        if (e < n_edges) atomicAdd(&h[dst[e] >> BSH], 1);
    }
    __syncthreads();
    for (int b = threadIdx.x; b < nbuck; b += 1024)
        if (h[b]) atomicAdd(&ghist[b], h[b]);
}

// ---- K2: exclusive scan of bucket counts -> gbase; init reservation counters
__global__ void k_scan(const int* __restrict__ ghist, int nbuck,
                       int* __restrict__ gbase, int* __restrict__ gfill) {
    __shared__ int s[MAXB];
    int t = threadIdx.x;                       // 512 threads
    s[t] = (t < nbuck) ? ghist[t] : 0;
    __syncthreads();
    for (int st = 1; st < MAXB; st <<= 1) {
        int v = (t >= st) ? s[t - st] : 0;
        __syncthreads();
        s[t] += v;
        __syncthreads();
    }
    if (t < nbuck) {
        int excl = s[t] - ghist[t];
        gbase[t] = excl;
        gfill[t] = excl;
    }
}

// ---- K3: partition edges into bucket-contiguous packed ebuf (src<<8 | dst&255)
__global__ void __launch_bounds__(1024)
k_part(const int* __restrict__ src, const int* __restrict__ dst,
       int n_edges, int nbuck, int* __restrict__ gfill, uint* __restrict__ ebuf) {
    __shared__ int hcnt[MAXB];
    __shared__ int hexcl[MAXB];   // inclusive scan; excl = hexcl-hcnt
    __shared__ int hrank[MAXB];
    __shared__ int hbase[MAXB];
    __shared__ uint2 stage[4096];
    int tid = threadIdx.x;
    for (int i = tid; i < MAXB; i += 1024) { hcnt[i] = 0; hrank[i] = 0; }
    __syncthreads();
    int base = blockIdx.x * 4096;
    int cnt = min(4096, n_edges - base);
    int s_[4], d_[4];
#pragma unroll
    for (int j = 0; j < 4; j++) {
        int k = j * 1024 + tid;
        if (k < cnt) {
            s_[j] = src[base + k]; d_[j] = dst[base + k];
            atomicAdd(&hcnt[d_[j] >> BSH], 1);
        }
    }
    __syncthreads();
    if (tid < MAXB) hexcl[tid] = hcnt[tid];
    __syncthreads();
    for (int st = 1; st < MAXB; st <<= 1) {
        int v = 0;
        if (tid < MAXB && tid >= st) v = hexcl[tid - st];
        __syncthreads();
        if (tid < MAXB) hexcl[tid] += v;
        __syncthreads();
    }
    if (tid < nbuck && hcnt[tid] > 0)
        hbase[tid] = atomicAdd(&gfill[tid], hcnt[tid]);
    __syncthreads();
#pragma unroll
    for (int j = 0; j < 4; j++) {
        int k = j * 1024 + tid;
        if (k < cnt) {
            int b = d_[j] >> BSH;
            int r = atomicAdd(&hrank[b], 1);
            stage[hexcl[b] - hcnt[b] + r] = make_uint2((uint)s_[j], (uint)d_[j]);
        }
    }
    __syncthreads();
    for (int t = tid; t < cnt; t += 1024) {
        uint2 e = stage[t];
        int b = (int)(e.y >> BSH);
        ebuf[hbase[b] + (t - (hexcl[b] - hcnt[b]))] = (e.x << 8) | (e.y & 255u);
    }
}

// ---- K4: per-bucket in-degree (real edges; +1 self-loop added in rsqrt)
__global__ void __launch_bounds__(1024)
k_deg2(const uint* __restrict__ ebuf, const int* __restrict__ gbase,
       const int* __restrict__ ghist, int n, int* __restrict__ deg) {
    __shared__ int nh[256];
    int tid = threadIdx.x;
    if (tid < 256) nh[tid] = 0;
    __syncthreads();
    int seg0 = gbase[blockIdx.x], cnt = ghist[blockIdx.x];
    for (int t = tid; t < cnt; t += 1024)
        atomicAdd(&nh[ebuf[seg0 + t] & 255u], 1);
    __syncthreads();
    int node = (blockIdx.x << BSH) + tid;
    if (tid < 256 && node < n) deg[node] = nh[tid];
}

// ---- K5: h = x @ W1 ; dinv = rsqrt(deg+1) ; Hs2 = bf16(h * dinv)
__global__ void k_gemm1(const float* __restrict__ x, const float* __restrict__ W1,
                        const int* __restrict__ deg, float* __restrict__ dinv,
                        uint* __restrict__ Hs2, int n) {
    __shared__ float Ws[N_FEAT * HIDDEN];   // 8 KB
    int tid = threadIdx.x;
    {
        const float4* w4 = (const float4*)W1;
        float4* s4 = (float4*)Ws;
        s4[tid * 2]     = w4[tid * 2];
        s4[tid * 2 + 1] = w4[tid * 2 + 1];
    }
    __syncthreads();
    int i = blockIdx.x * blockDim.x + tid;
    if (i >= n) return;

    float acc[HIDDEN];
#pragma unroll
    for (int o = 0; o < HIDDEN; o++) acc[o] = 0.f;

    const float4* xr = (const float4*)(x + (size_t)i * N_FEAT);
#pragma unroll 8
    for (int k4 = 0; k4 < N_FEAT / 4; k4++) {
        float4 xv = xr[k4];
        const float* w0 = &Ws[(k4 * 4 + 0) * HIDDEN];
        const float* w1 = &Ws[(k4 * 4 + 1) * HIDDEN];
        const float* w2 = &Ws[(k4 * 4 + 2) * HIDDEN];
        const float* w3 = &Ws[(k4 * 4 + 3) * HIDDEN];
#pragma unroll
        for (int o = 0; o < HIDDEN; o++)
            acc[o] += xv.x * w0[o] + xv.y * w1[o] + xv.z * w2[o] + xv.w * w3[o];
    }
    float di = rsqrtf((float)deg[i] + 1.0f);
    dinv[i] = di;
    uint o8[8];
#pragma unroll
    for (int j = 0; j < 8; j++) o8[j] = pk2(acc[2 * j] * di, acc[2 * j + 1] * di);
    uint4* hp = (uint4*)(Hs2 + (size_t)i * 8);
    hp[0] = make_uint4(o8[0], o8[1], o8[2], o8[3]);
    hp[1] = make_uint4(o8[4], o8[5], o8[6], o8[7]);
}

// ---- K6: layer-1 aggregation per bucket: Q = relu(dinv*(sum Hs[nbr] + Hs[self]) + b1)*dinv
__global__ void __launch_bounds__(1024)
k_agg1(const uint* __restrict__ ebuf, const int* __restrict__ gbase,
       const int* __restrict__ ghist, const uint* __restrict__ Hs2,
       const float* __restrict__ dinv, const float* __restrict__ b1,
       uint* __restrict__ Q2, int n) {
    __shared__ float Qa[256 * 17];   // +1 pad breaks bank alignment
    __shared__ float b1s[HIDDEN];
    int tid = threadIdx.x;
    for (int i = tid; i < 256 * 17; i += 1024) Qa[i] = 0.f;
    if (tid < HIDDEN) b1s[tid] = b1[tid];
    __syncthreads();
    int seg0 = gbase[blockIdx.x], cnt = ghist[blockIdx.x];
    int gid = tid >> 3, fp = tid & 7;            // 128 groups x 8 lanes
    for (int t = gid; t < cnt; t += 128) {
        uint e = ebuf[seg0 + t];                 // broadcast within group
        int s = (int)(e >> 8), ln = (int)(e & 255u);
        float2 v = upk2(Hs2[(size_t)s * 8 + fp]);
        atomicAdd(&Qa[ln * 17 + 2 * fp],     v.x);
        atomicAdd(&Qa[ln * 17 + 2 * fp + 1], v.y);
    }
    __syncthreads();
    int node = (blockIdx.x << BSH) + tid;
    if (tid < 256 && node < n) {
        float di = dinv[node];
        float q[HIDDEN];
#pragma unroll
        for (int j = 0; j < 8; j++) {
            float2 h = upk2(Hs2[(size_t)node * 8 + j]);   // self-loop
            q[2 * j]     = Qa[tid * 17 + 2 * j]     + h.x;
            q[2 * j + 1] = Qa[tid * 17 + 2 * j + 1] + h.y;
        }
        uint o8[8];
#pragma unroll
        for (int j = 0; j < 8; j++) {
            float a = fmaxf(di * q[2 * j]     + b1s[2 * j],     0.f) * di;
            float b = fmaxf(di * q[2 * j + 1] + b1s[2 * j + 1], 0.f) * di;
            o8[j] = pk2(a, b);
        }
        uint4* qp = (uint4*)(Q2 + (size_t)node * 8);
        qp[0] = make_uint4(o8[0], o8[1], o8[2], o8[3]);
        qp[1] = make_uint4(o8[4], o8[5], o8[6], o8[7]);
    }
}

// ---- K7: self term + counts: S[g] += dinv[i]*Q[i], cnt[g] += 1 (sorted batch)
__global__ void k_selfpool(const uint* __restrict__ Q2, const int* __restrict__ batch,
                           const float* __restrict__ dinv,
                           float* __restrict__ S, float* __restrict__ cnt, int n) {
    __shared__ float ls[8 * HIDDEN];
    __shared__ float lc[8];
    int tid = threadIdx.x;
    if (tid < 8) lc[tid] = 0.f;
    if (tid < 8 * HIDDEN) ls[tid] = 0.f;
    __syncthreads();
    int i0 = blockIdx.x * 256;
    int g0 = batch[i0 < n ? i0 : (n - 1)];
    int i = i0 + tid;
    if (i < n) {
        int g = batch[i];
        float di = dinv[i];
        float r[HIDDEN];
#pragma unroll
        for (int j = 0; j < 8; j++) {
            float2 v = upk2(Q2[(size_t)i * 8 + j]);
            r[2 * j] = di * v.x; r[2 * j + 1] = di * v.y;
        }
        int off = g - g0;
        if (off >= 0 && off < 8) {
#pragma unroll
            for (int o = 0; o < HIDDEN; o++) atomicAdd(&ls[off * HIDDEN + o], r[o]);
            atomicAdd(&lc[off], 1.f);
        } else {
#pragma unroll
            for (int o = 0; o < HIDDEN; o++) atomicAdd(&S[(size_t)g * HIDDEN + o], r[o]);
            atomicAdd(&cnt[g], 1.f);
        }
    }
    __syncthreads();
    if (tid < 8 * HIDDEN) {
        int b = tid >> 4, o = tid & 15;
        int g = g0 + b;
        float v = ls[b * HIDDEN + o];
        if (v != 0.f && g < N_GRAPHS) atomicAdd(&S[(size_t)g * HIDDEN + o], v);
    }
    if (tid < 8) {
        int g = g0 + tid;
        float c = lc[tid];
        if (c != 0.f && g < N_GRAPHS) atomicAdd(&cnt[g], c);
    }
}

// ---- K8: edge terms of layer2+pool: S[batch[d]] += dinv[d]*Q[s] per bucket
__global__ void __launch_bounds__(1024)
k_edge2(const uint* __restrict__ ebuf, const int* __restrict__ gbase,
        const int* __restrict__ ghist, const uint* __restrict__ Q2,
        const int* __restrict__ batch, const float* __restrict__ dinv,
        float* __restrict__ S, int n) {
    __shared__ float Sl[N_GRAPHS * HIDDEN];   // 4 KB
    __shared__ int   batL[256];
    __shared__ float dinvL[256];
    int tid = threadIdx.x;
    Sl[tid] = 0.f;   // blockDim == 1024 == N_GRAPHS*HIDDEN
    if (tid < 256) {
        int node = (blockIdx.x << BSH) + tid;
        batL[tid]  = (node < n) ? batch[node] : 0;
        dinvL[tid] = (node < n) ? dinv[node]  : 0.f;
    }
    __syncthreads();
    int seg0 = gbase[blockIdx.x], cnt = ghist[blockIdx.x];
    int gid = tid >> 3, fp = tid & 7;
    int gc = -1;
    float ax = 0.f, ay = 0.f;
    for (int t = gid; t < cnt; t += 128) {
        uint e = ebuf[seg0 + t];
        int s = (int)(e >> 8), ln = (int)(e & 255u);
        int g = batL[ln];                  // uniform within 8-lane group
        if (g != gc) {
            if (gc >= 0) {
                atomicAdd(&Sl[gc * HIDDEN + 2 * fp],     ax);
                atomicAdd(&Sl[gc * HIDDEN + 2 * fp + 1], ay);
            }
            gc = g; ax = 0.f; ay = 0.f;
        }
        float di = dinvL[ln];
        float2 v = upk2(Q2[(size_t)s * 8 + fp]);
        ax += di * v.x; ay += di * v.y;
    }
    if (gc >= 0) {
        atomicAdd(&Sl[gc * HIDDEN + 2 * fp],     ax);
        atomicAdd(&Sl[gc * HIDDEN + 2 * fp + 1], ay);
    }
    __syncthreads();
    float v = Sl[tid];
    if (v != 0.f) atomicAdd(&S[tid], v);
}

// ---- K9: out[g][e] = (S[g]/cnt[g]) @ W2 + b2
__global__ void k_out(const float* __restrict__ S, const float* __restrict__ cnt,
                      const float* __restrict__ W2, const float* __restrict__ b2,
                      float* __restrict__ out) {
    int g = blockIdx.x;
    int e = threadIdx.x;
    float c = cnt[g];
    float acc = 0.f;
#pragma unroll
    for (int k = 0; k < HIDDEN; k++) acc += S[g * HIDDEN + k] * W2[k * EMBED + e];
    out[g * EMBED + e] = (c > 0.f) ? (acc / c + b2[e]) : 0.f;
}

extern "C" void kernel_launch(void* const* d_in, const int* in_sizes, int n_in,
                              void* d_out, int out_size, void* d_ws, size_t ws_size,
                              hipStream_t stream) {
    const float* x     = (const float*)d_in[0];
    const int*   ei    = (const int*)  d_in[1];
    const int*   batch = (const int*)  d_in[2];
    const float* W1    = (const float*)d_in[3];
    const float* b1    = (const float*)d_in[4];
    const float* W2    = (const float*)d_in[5];
    const float* b2    = (const float*)d_in[6];
    float* out = (float*)d_out;

    const int n       = in_sizes[2];
    const int n_edges = in_sizes[1] / 2;
    const int* srcp = ei;
    const int* dstp = ei + n_edges;
    const int nbuck = (n + 255) >> BSH;      // 391

    // workspace layout
    uint*  Hs2   = (uint*)d_ws;                  // n*8 uints (bf16x2)
    uint*  Q2    = Hs2 + (size_t)n * 8;          // n*8 uints
    float* dinv  = (float*)(Q2 + (size_t)n * 8); // n
    int*   deg   = (int*)(dinv + n);             // n
    uint*  ebuf  = (uint*)(deg + n);             // n_edges
    int*   ghist = (int*)(ebuf + n_edges);       // MAXB
    int*   gbase = ghist + MAXB;                 // MAXB
    int*   gfill = gbase + MAXB;                 // MAXB
    float* S     = (float*)(gfill + MAXB);       // 64*16
    float* cnt   = S + N_GRAPHS * HIDDEN;        // 64

    hipMemsetAsync(ghist, 0, MAXB * sizeof(int), stream);
    hipMemsetAsync(S, 0, (N_GRAPHS * HIDDEN + N_GRAPHS) * sizeof(float), stream);

    const int pb4k = (n_edges + 4095) / 4096;   // 391
    k_hist <<<pb4k, 1024, 0, stream>>>(dstp, n_edges, nbuck, ghist);
    k_scan <<<1, MAXB, 0, stream>>>(ghist, nbuck, gbase, gfill);
    k_part <<<pb4k, 1024, 0, stream>>>(srcp, dstp, n_edges, nbuck, gfill, ebuf);
    k_deg2 <<<nbuck, 1024, 0, stream>>>(ebuf, gbase, ghist, n, deg);

    const int nb = (n + 255) / 256;
    k_gemm1<<<nb, 256, 0, stream>>>(x, W1, deg, dinv, Hs2, n);
    k_agg1 <<<nbuck, 1024, 0, stream>>>(ebuf, gbase, ghist, Hs2, dinv, b1, Q2, n);
    k_selfpool<<<nb, 256, 0, stream>>>(Q2, batch, dinv, S, cnt, n);
    k_edge2<<<nbuck, 1024, 0, stream>>>(ebuf, gbase, ghist, Q2, batch, dinv, S, n);
    k_out  <<<N_GRAPHS, EMBED, 0, stream>>>(S, cnt, W2, b2, out);
}

// Round 7
// 255.138 us; speedup vs baseline: 1.6671x; 1.6671x over previous
//
#include <hip/hip_runtime.h>

#define HIDDEN 16
#define N_FEAT 128
#define EMBED 128
#define N_GRAPHS 64
#define BSH 8              // 256 nodes per bucket
#define MAXB 512           // LDS bound on bucket count (nbuck = 391 here)

typedef unsigned int uint;

// bf16x2 pack/unpack (round-to-nearest-even)
__device__ inline uint pk2(float a, float b) {
    uint ua = __float_as_uint(a), ub = __float_as_uint(b);
    ua = (ua + 0x7FFFu + ((ua >> 16) & 1u)) >> 16;
    ub = (ub + 0x7FFFu + ((ub >> 16) & 1u)) & 0xFFFF0000u;
    return ua | ub;
}
__device__ inline float2 upk2(uint w) {
    return make_float2(__uint_as_float(w << 16), __uint_as_float(w & 0xFFFF0000u));
}

// ---- K1: global bucket histogram of dst>>BSH
__global__ void __launch_bounds__(1024)
k_hist(const int* __restrict__ dst, int n_edges, int nbuck, int* __restrict__ ghist) {
    __shared__ int h[MAXB];
    for (int i = threadIdx.x; i < MAXB; i += 1024) h[i] = 0;
    __syncthreads();
    int base = blockIdx.x * 4096;
#pragma unroll
    for (int j = 0; j < 4; j++) {
        int e = base + j * 1024 + threadIdx.x;
        if (e < n_edges) atomicAdd(&h[dst[e] >> BSH], 1);
    }
    __syncthreads();
    for (int b = threadIdx.x; b < nbuck; b += 1024)
        if (h[b]) atomicAdd(&ghist[b], h[b]);
}

// ---- K2: exclusive scan of bucket counts -> gbase; init reservation counters
__global__ void k_scan(const int* __restrict__ ghist, int nbuck,
                       int* __restrict__ gbase, int* __restrict__ gfill) {
    __shared__ int s[MAXB];
    int t = threadIdx.x;                       // 512 threads
    s[t] = (t < nbuck) ? ghist[t] : 0;
    __syncthreads();
    for (int st = 1; st < MAXB; st <<= 1) {
        int v = (t >= st) ? s[t - st] : 0;
        __syncthreads();
        s[t] += v;
        __syncthreads();
    }
    if (t < nbuck) {
        int excl = s[t] - ghist[t];
        gbase[t] = excl;
        gfill[t] = excl;
    }
}

// ---- K3: partition edges into bucket-contiguous packed ebuf (src<<8 | dst&255)
__global__ void __launch_bounds__(1024)
k_part(const int* __restrict__ src, const int* __restrict__ dst,
       int n_edges, int nbuck, int* __restrict__ gfill, uint* __restrict__ ebuf) {
    __shared__ int hcnt[MAXB];
    __shared__ int hexcl[MAXB];   // inclusive scan; excl = hexcl-hcnt
    __shared__ int hrank[MAXB];
    __shared__ int hbase[MAXB];
    __shared__ uint stage[4096];
    int tid = threadIdx.x;
    for (int i = tid; i < MAXB; i += 1024) { hcnt[i] = 0; hrank[i] = 0; }
    __syncthreads();
    int base = blockIdx.x * 4096;
    int cnt = min(4096, n_edges - base);
    int s_[4], d_[4];
#pragma unroll
    for (int j = 0; j < 4; j++) {
        int k = j * 1024 + tid;
        if (k < cnt) {
            s_[j] = src[base + k]; d_[j] = dst[base + k];
            atomicAdd(&hcnt[d_[j] >> BSH], 1);
        }
    }
    __syncthreads();
    if (tid < MAXB) hexcl[tid] = hcnt[tid];
    __syncthreads();
    for (int st = 1; st < MAXB; st <<= 1) {
        int v = 0;
        if (tid < MAXB && tid >= st) v = hexcl[tid - st];
        __syncthreads();
        if (tid < MAXB) hexcl[tid] += v;
        __syncthreads();
    }
    if (tid < nbuck && hcnt[tid] > 0)
        hbase[tid] = atomicAdd(&gfill[tid], hcnt[tid]);
    __syncthreads();
#pragma unroll
    for (int j = 0; j < 4; j++) {
        int k = j * 1024 + tid;
        if (k < cnt) {
            int b = d_[j] >> BSH;
            int r = atomicAdd(&hrank[b], 1);
            stage[hexcl[b] - hcnt[b] + r] = ((uint)s_[j] << 8) | ((uint)d_[j] & 255u);
        }
    }
    __syncthreads();
    for (int t = tid; t < cnt; t += 1024) {
        uint e = stage[t];
        // recover bucket id of staged position t: first b with t < hexcl[b]
        int lo = 0, hi = MAXB - 1;
        while (lo < hi) {
            int mid = (lo + hi) >> 1;
            if (t < hexcl[mid]) hi = mid; else lo = mid + 1;
        }
        int b = lo;
        ebuf[hbase[b] + (t - (hexcl[b] - hcnt[b]))] = e;
    }
}

// ---- K4: per-bucket CSR finalize from packed ebuf: deg, rowptr, col
__global__ void __launch_bounds__(1024)
k_csr(const uint* __restrict__ ebuf, const int* __restrict__ gbase,
      const int* __restrict__ ghist, int n,
      int* __restrict__ deg, int* __restrict__ rowp, int* __restrict__ col) {
    __shared__ int nh[256], nexcl[256], nrank[256];
    int b = blockIdx.x;
    int tid = threadIdx.x;
    int seg0 = gbase[b];
    int cnt = ghist[b];
    int nb0 = b << BSH;
    if (tid < 256) { nh[tid] = 0; nrank[tid] = 0; }
    __syncthreads();
    for (int t = tid; t < cnt; t += 1024)
        atomicAdd(&nh[ebuf[seg0 + t] & 255u], 1);
    __syncthreads();
    if (tid < 256) nexcl[tid] = nh[tid];
    __syncthreads();
    for (int st = 1; st < 256; st <<= 1) {
        int v = 0;
        if (tid < 256 && tid >= st) v = nexcl[tid - st];
        __syncthreads();
        if (tid < 256) nexcl[tid] += v;
        __syncthreads();
    }
    if (tid < 256) {
        int node = nb0 + tid;
        if (node < n) {
            deg[node]  = nh[tid];
            rowp[node] = seg0 + nexcl[tid] - nh[tid];
        }
    }
    __syncthreads();
    for (int t = tid; t < cnt; t += 1024) {
        uint e = ebuf[seg0 + t];
        int ln = (int)(e & 255u);
        int r = atomicAdd(&nrank[ln], 1);
        col[seg0 + (nexcl[ln] - nh[ln]) + r] = (int)(e >> 8);
    }
}

// ---- K5: h = x @ W1 ; dinv = rsqrt(deg+1) ; Hs2 = bf16(h * dinv)
__global__ void k_gemm1(const float* __restrict__ x, const float* __restrict__ W1,
                        const int* __restrict__ deg, float* __restrict__ dinv,
                        uint* __restrict__ Hs2, int n) {
    __shared__ float Ws[N_FEAT * HIDDEN];   // 8 KB
    int tid = threadIdx.x;
    {
        const float4* w4 = (const float4*)W1;
        float4* s4 = (float4*)Ws;
        s4[tid * 2]     = w4[tid * 2];
        s4[tid * 2 + 1] = w4[tid * 2 + 1];
    }
    __syncthreads();
    int i = blockIdx.x * blockDim.x + tid;
    if (i >= n) return;

    float acc[HIDDEN];
#pragma unroll
    for (int o = 0; o < HIDDEN; o++) acc[o] = 0.f;

    const float4* xr = (const float4*)(x + (size_t)i * N_FEAT);
#pragma unroll 8
    for (int k4 = 0; k4 < N_FEAT / 4; k4++) {
        float4 xv = xr[k4];
        const float* w0 = &Ws[(k4 * 4 + 0) * HIDDEN];
        const float* w1 = &Ws[(k4 * 4 + 1) * HIDDEN];
        const float* w2 = &Ws[(k4 * 4 + 2) * HIDDEN];
        const float* w3 = &Ws[(k4 * 4 + 3) * HIDDEN];
#pragma unroll
        for (int o = 0; o < HIDDEN; o++)
            acc[o] += xv.x * w0[o] + xv.y * w1[o] + xv.z * w2[o] + xv.w * w3[o];
    }
    float di = rsqrtf((float)deg[i] + 1.0f);
    dinv[i] = di;
    uint o8[8];
#pragma unroll
    for (int j = 0; j < 8; j++) o8[j] = pk2(acc[2 * j] * di, acc[2 * j + 1] * di);
    uint4* hp = (uint4*)(Hs2 + (size_t)i * 8);
    hp[0] = make_uint4(o8[0], o8[1], o8[2], o8[3]);
    hp[1] = make_uint4(o8[4], o8[5], o8[6], o8[7]);
}

// ---- K6: pull-mode aggregation, bf16 table: one wave per node, 8 edges x 8 uints
// LAYER 1: Q2 = bf16( relu(dinv*(sum+self) + b1) * dinv )
// LAYER 2: R2 = f32  ( dinv*(sum+self) )
template <int LAYER>
__global__ void k_pull(const uint* __restrict__ V2, const int* __restrict__ rowptr,
                       const int* __restrict__ deg, const int* __restrict__ col,
                       const float* __restrict__ dinv, const float* __restrict__ b1,
                       uint* __restrict__ Q2, float2* __restrict__ R2, int n) {
    int wid = (blockIdx.x * blockDim.x + threadIdx.x) >> 6;
    int lane = threadIdx.x & 63;
    if (wid >= n) return;
    int f  = lane & 7;    // uint slot (2 features)
    int es = lane >> 3;   // edge slot 0..7
    int start = rowptr[wid];
    int dg = deg[wid];
    float ax = 0.f, ay = 0.f;
    for (int j = es; j < dg; j += 8) {
        int s = col[start + j];
        float2 v = upk2(V2[(size_t)s * 8 + f]);
        ax += v.x; ay += v.y;
    }
    ax += __shfl_xor(ax, 8, 64);  ay += __shfl_xor(ay, 8, 64);
    ax += __shfl_xor(ax, 16, 64); ay += __shfl_xor(ay, 16, 64);
    ax += __shfl_xor(ax, 32, 64); ay += __shfl_xor(ay, 32, 64);
    if (lane < 8) {
        float2 h = upk2(V2[(size_t)wid * 8 + f]);   // self-loop
        float tx = ax + h.x, ty = ay + h.y;
        float di = dinv[wid];
        if (LAYER == 1) {
            float qa = fmaxf(di * tx + b1[2 * f],     0.f) * di;
            float qb = fmaxf(di * ty + b1[2 * f + 1], 0.f) * di;
            Q2[(size_t)wid * 8 + f] = pk2(qa, qb);
        } else {
            R2[(size_t)wid * 8 + f] = make_float2(di * tx, di * ty);
        }
    }
}

// ---- K7: pooling: S[batch] += R; cnt[batch] += 1 (sorted batch -> LDS buckets)
__global__ void k_pool(const float* __restrict__ R, const int* __restrict__ batch,
                       float* __restrict__ S, float* __restrict__ cnt, int n) {
    __shared__ float ls[8 * HIDDEN];
    __shared__ float lc[8];
    int tid = threadIdx.x;
    if (tid < 8) lc[tid] = 0.f;
    if (tid < 8 * HIDDEN) ls[tid] = 0.f;
    __syncthreads();

    int i0 = blockIdx.x * 256;
    int g0 = batch[i0 < n ? i0 : (n - 1)];
    int i = i0 + tid;
    if (i < n) {
        int g = batch[i];
        const float* r = R + (size_t)i * HIDDEN;
        int off = g - g0;
        if (off >= 0 && off < 8) {
#pragma unroll
            for (int o = 0; o < HIDDEN; o++) atomicAdd(&ls[off * HIDDEN + o], r[o]);
            atomicAdd(&lc[off], 1.f);
        } else {
#pragma unroll
            for (int o = 0; o < HIDDEN; o++) atomicAdd(&S[(size_t)g * HIDDEN + o], r[o]);
            atomicAdd(&cnt[g], 1.f);
        }
    }
    __syncthreads();
    if (tid < 8 * HIDDEN) {
        int b = tid >> 4, o = tid & 15;
        int g = g0 + b;
        float v = ls[b * HIDDEN + o];
        if (v != 0.f && g < N_GRAPHS) atomicAdd(&S[(size_t)g * HIDDEN + o], v);
    }
    if (tid < 8) {
        int g = g0 + tid;
        float c = lc[tid];
        if (c != 0.f && g < N_GRAPHS) atomicAdd(&cnt[g], c);
    }
}

// ---- K8: out[g][e] = (S[g]/cnt[g]) @ W2 + b2
__global__ void k_out(const float* __restrict__ S, const float* __restrict__ cnt,
                      const float* __restrict__ W2, const float* __restrict__ b2,
                      float* __restrict__ out) {
    int g = blockIdx.x;
    int e = threadIdx.x;
    float c = cnt[g];
    float acc = 0.f;
#pragma unroll
    for (int k = 0; k < HIDDEN; k++) acc += S[g * HIDDEN + k] * W2[k * EMBED + e];
    out[g * EMBED + e] = (c > 0.f) ? (acc / c + b2[e]) : 0.f;
}

extern "C" void kernel_launch(void* const* d_in, const int* in_sizes, int n_in,
                              void* d_out, int out_size, void* d_ws, size_t ws_size,
                              hipStream_t stream) {
    const float* x     = (const float*)d_in[0];
    const int*   ei    = (const int*)  d_in[1];
    const int*   batch = (const int*)  d_in[2];
    const float* W1    = (const float*)d_in[3];
    const float* b1    = (const float*)d_in[4];
    const float* W2    = (const float*)d_in[5];
    const float* b2    = (const float*)d_in[6];
    float* out = (float*)d_out;

    const int n       = in_sizes[2];
    const int n_edges = in_sizes[1] / 2;
    const int* srcp = ei;
    const int* dstp = ei + n_edges;
    const int nbuck = (n + 255) >> BSH;      // 391

    // workspace layout
    uint*  Hs2   = (uint*)d_ws;                  // n*8 uints (bf16x2)
    uint*  Q2    = Hs2 + (size_t)n * 8;          // n*8 uints
    float* dinv  = (float*)(Q2 + (size_t)n * 8); // n
    int*   deg   = (int*)(dinv + n);             // n
    int*   rowp  = deg + n;                      // n
    int*   col   = rowp + n;                     // n_edges
    uint*  ebuf  = (uint*)(col + n_edges);       // n_edges (R overlays after k_csr)
    int*   ghist = (int*)(ebuf + n_edges);       // MAXB
    int*   gbase = ghist + MAXB;                 // MAXB
    int*   gfill = gbase + MAXB;                 // MAXB
    float* S     = (float*)(gfill + MAXB);       // 64*16
    float* cnt   = S + N_GRAPHS * HIDDEN;        // 64
    float* R     = (float*)ebuf;                 // n*16 floats == n_edges*4B exactly

    hipMemsetAsync(ghist, 0, MAXB * sizeof(int), stream);
    hipMemsetAsync(S, 0, (N_GRAPHS * HIDDEN + N_GRAPHS) * sizeof(float), stream);

    const int pb4k = (n_edges + 4095) / 4096;   // 391
    k_hist <<<pb4k, 1024, 0, stream>>>(dstp, n_edges, nbuck, ghist);
    k_scan <<<1, MAXB, 0, stream>>>(ghist, nbuck, gbase, gfill);
    k_part <<<pb4k, 1024, 0, stream>>>(srcp, dstp, n_edges, nbuck, gfill, ebuf);
    k_csr  <<<nbuck, 1024, 0, stream>>>(ebuf, gbase, ghist, n, deg, rowp, col);

    const int nb = (n + 255) / 256;
    k_gemm1<<<nb, 256, 0, stream>>>(x, W1, deg, dinv, Hs2, n);

    const int pullb = (n * 64 + 255) / 256;
    k_pull<1><<<pullb, 256, 0, stream>>>(Hs2, rowp, deg, col, dinv, b1, Q2, (float2*)R, n);
    k_pull<2><<<pullb, 256, 0, stream>>>(Q2,  rowp, deg, col, dinv, b1, Hs2, (float2*)R, n);

    k_pool <<<nb, 256, 0, stream>>>(R, batch, S, cnt, n);
    k_out  <<<N_GRAPHS, EMBED, 0, stream>>>(S, cnt, W2, b2, out);
}